// Round 1
// baseline (1347.113 us; speedup 1.0000x reference)
//
#include <hip/hip_runtime.h>
#include <math.h>

#define CC 32
#define LL 16
#define HH 64
#define WW 64
#define WF 33
#define RR 16
#define PI_F 3.14159265358979323846f

// ---- workspace layout (floats). Regions reused across phases. ----
#define OFF_F1      0          // 2097152  f1 (conv1 out); later reused as Y2 (pif out / normalized z)
#define OFF_COLSUM  2097152    // 32768    [l][c][w] column sums of silu(conv2)
#define OFF_GSUM    2129920    // 512      [l][c] total sums
#define OFF_GLOB    2130432    // 512      [l][c] sigmoid gate
#define OFF_FEAT    2130944    // 16896    [l][wf][c]
#define OFF_ARE     2147840    // 270336   [l][c][wf][r]
#define OFF_AIM     2418176    // 270336
#define OFF_SGG     2688512    // 270336   sg * g(l)
#define OFF_XFR     2958848    // 1081344  [l][c][h][f]  (region + XFI reused as Y1 after scan)
#define OFF_XFI     4040192    // 1081344
#define OFF_YFR     5121536    // 1081344
#define OFF_YFI     6202880    // 1081344
#define OFF_Y1      2958848    // 2097152  irfft out [l][c][h][w] (overlaps dead XFR/XFI)
#define OFF_Y2      0          // 2097152  pif out / z (overlaps dead F1)
#define OFF_GNM     7284224    // 64
#define OFF_GNR     7284288    // 64
#define OFF_YM      7284352    // 32768    [l][h][c]
#define OFF_GATE    7317120    // 32768    [l][h][c]
#define OFF_WVEC    7349888    // 66: w_re[32], w_im[32], c_re, c_im
// total 7349954 floats = 29.4 MB

__device__ __forceinline__ float sigmoidf_(float x){ return 1.0f/(1.0f+expf(-x)); }

// ---- K0: collapse mix/rank_scale/proj into two 32-vectors ----
__global__ void k_prep(const float* __restrict__ mix_w, const float* __restrict__ mix_b,
                       const float* __restrict__ rank_scale, const float* __restrict__ proj_w,
                       const float* __restrict__ proj_b, float* __restrict__ ws){
    float* wv = ws + OFF_WVEC;
    int t = threadIdx.x;
    if (t < 32){
        float sre=0.f, sim=0.f;
        for (int r=0;r<RR;r++){
            float a = proj_w[r]*rank_scale[r];
            sre += a*mix_w[r*2*RR + t];
            sim += a*mix_w[(RR+r)*2*RR + t];
        }
        wv[t] = sre;
        wv[32+t] = sim;
    }
    if (t == 0){
        float cre=0.f, cim=0.f;
        for (int r=0;r<RR;r++){
            float a = proj_w[r]*rank_scale[r];
            cre += a*mix_b[r];
            cim += a*mix_b[RR+r];
        }
        wv[64] = cre + proj_b[0];
        wv[65] = cim;
    }
}

// ---- K1: conv1 (3x3 SAME, 32->32) + SiLU. Block = (l, c_out). ----
__global__ void k_conv1(const float* __restrict__ x, const float* __restrict__ cw,
                        const float* __restrict__ cb, float* __restrict__ ws){
    __shared__ float lw[CC*9];
    int b = blockIdx.x;
    int l = b >> 5, co = b & 31;
    int tid = threadIdx.x;
    for (int i = tid; i < CC*9; i += 256) lw[i] = cw[co*CC*9 + i];
    __syncthreads();
    float bias = cb[co];
    float* f1 = ws + OFF_F1 + (l*CC + co)*HH*WW;
    for (int k = 0; k < 16; k++){
        int pix = tid + k*256;
        int h = pix >> 6, w = pix & 63;
        float acc = bias;
        for (int ci = 0; ci < CC; ci++){
            const float* xp = x + (ci*LL + l)*HH*WW;
            const float* wp = lw + ci*9;
            #pragma unroll
            for (int kh = 0; kh < 3; kh++){
                int hh = h + kh - 1;
                if (hh < 0 || hh >= HH) continue;
                const float* xr = xp + hh*WW;
                #pragma unroll
                for (int kw = 0; kw < 3; kw++){
                    int wwi = w + kw - 1;
                    if (wwi < 0 || wwi >= WW) continue;
                    acc += xr[wwi]*wp[kh*3+kw];
                }
            }
        }
        acc = acc * sigmoidf_(acc);
        f1[pix] = acc;
    }
}

// ---- K2: conv2 + SiLU, reduced directly to colsum[l][c][w] and total sum ----
__global__ void k_conv2(const float* __restrict__ cw, const float* __restrict__ cb,
                        float* __restrict__ ws){
    __shared__ float lw[CC*9];
    __shared__ float red[256];
    int b = blockIdx.x;
    int l = b >> 5, co = b & 31;
    int tid = threadIdx.x;
    for (int i = tid; i < CC*9; i += 256) lw[i] = cw[co*CC*9 + i];
    __syncthreads();
    float bias = cb[co];
    const float* f1 = ws + OFF_F1 + (l*CC)*HH*WW;
    int w = tid & 63, hb = tid >> 6;
    float colpart = 0.f;
    for (int k = 0; k < 16; k++){
        int h = hb + k*4;
        float acc = bias;
        for (int ci = 0; ci < CC; ci++){
            const float* xp = f1 + ci*HH*WW;
            const float* wp = lw + ci*9;
            #pragma unroll
            for (int kh = 0; kh < 3; kh++){
                int hh = h + kh - 1;
                if (hh < 0 || hh >= HH) continue;
                const float* xr = xp + hh*WW;
                #pragma unroll
                for (int kw = 0; kw < 3; kw++){
                    int wwi = w + kw - 1;
                    if (wwi < 0 || wwi >= WW) continue;
                    acc += xr[wwi]*wp[kh*3+kw];
                }
            }
        }
        acc = acc * sigmoidf_(acc);
        colpart += acc;
    }
    red[tid] = colpart;
    __syncthreads();
    if (tid < 64){
        float c = red[tid] + red[tid+64] + red[tid+128] + red[tid+192];
        ws[OFF_COLSUM + (l*CC+co)*WW + tid] = c;
        red[tid] = c;
    }
    __syncthreads();
    if (tid < 32) red[tid] += red[tid+32];
    __syncthreads();
    if (tid == 0){
        float s = 0.f;
        for (int i=0;i<32;i++) s += red[i];
        ws[OFF_GSUM + l*CC + co] = s;
    }
}

// ---- K3: glob = sigmoid(mean @ gfc_w.T + b) ----
__global__ void k_glob(const float* __restrict__ gfc_w, const float* __restrict__ gfc_b,
                       float* __restrict__ ws){
    int t = blockIdx.x*blockDim.x + threadIdx.x;
    if (t >= LL*CC) return;
    int l = t >> 5, o = t & 31;
    const float* gs = ws + OFF_GSUM + l*CC;
    float acc = gfc_b[o];
    for (int i=0;i<CC;i++) acc += gs[i]*(1.0f/4096.0f)*gfc_w[o*CC+i];
    ws[OFF_GLOB + t] = sigmoidf_(acc);
}

// ---- K4: adaptive avg pool over W (64->33), times glob ----
__global__ void k_feat(float* __restrict__ ws){
    int t = blockIdx.x*blockDim.x + threadIdx.x;
    if (t >= LL*WF*CC) return;
    int c = t & 31;
    int lw_ = t >> 5;           // l*33 + wf
    int wf = lw_ % WF, l = lw_ / WF;
    int s = (wf*64)/33;
    int e = ((wf+1)*64 + 32)/33;
    const float* cs = ws + OFF_COLSUM + (l*CC+c)*WW;
    float sum = 0.f;
    for (int w=s;w<e;w++) sum += cs[w];
    ws[OFF_FEAT + (l*WF+wf)*CC + c] = ws[OFF_GLOB + l*CC + c] * sum / (64.0f*(float)(e-s));
}

// ---- K5: head matmul + activations -> A (complex decay) and sg*g ----
__global__ void k_head(const float* __restrict__ hw, const float* __restrict__ hb,
                       const float* __restrict__ dt, float* __restrict__ ws){
    int t = blockIdx.x*blockDim.x + threadIdx.x;
    if (t >= LL*WF*CC*RR) return;
    int r = t & 15, c = (t>>4) & 31;
    int lw_ = t >> 9;
    int wf = lw_ % WF, l = lw_ / WF;
    const float* feat = ws + OFF_FEAT + (l*WF+wf)*CC;
    int j0 = (c*RR + r)*3;
    const float* w0 = hw + j0*CC;
    float p0=hb[j0], p1=hb[j0+1], p2=hb[j0+2];
    for (int i=0;i<CC;i++){
        float fv = feat[i];
        p0 += fv*w0[i]; p1 += fv*w0[CC+i]; p2 += fv*w0[2*CC+i];
    }
    float nu = fmaxf(p0,0.f) + log1pf(expf(-fabsf(p0)));   // softplus
    float th = tanhf(p1)*PI_F;
    float sg = sigmoidf_(p2);
    float dtv = dt[l];
    float decay = expf(-nu*dtv);
    float ang = th*dtv;
    float g = 1.0f - expf(-2.0f*fmaxf(dtv,0.f));
    int idx = ((l*CC+c)*WF+wf)*RR + r;
    ws[OFF_ARE+idx] = decay*cosf(ang);
    ws[OFF_AIM+idx] = decay*sinf(ang);
    ws[OFF_SGG+idx] = sg*g;
}

// ---- K6: rfft over W (direct DFT, 64-pt, 33 bins). Block = (l,c). ----
__global__ void k_rfft(const float* __restrict__ x, float* __restrict__ ws){
    __shared__ float plane[HH][WW+1];
    __shared__ float ct[64], st[64];
    int b = blockIdx.x; int l = b >> 5, c = b & 31;
    int tid = threadIdx.x;
    if (tid < 64){
        float ang = 2.0f*PI_F*(float)tid/64.0f;
        ct[tid] = cosf(ang); st[tid] = sinf(ang);
    }
    const float* xp = x + (c*LL + l)*HH*WW;
    for (int k=0;k<16;k++){
        int pix = tid + k*256;
        plane[pix>>6][pix&63] = xp[pix];
    }
    __syncthreads();
    float* xfr = ws + OFF_XFR + (l*CC + c)*HH*WF;
    float* xfi = ws + OFF_XFI + (l*CC + c)*HH*WF;
    for (int k=0;k<9;k++){
        int oi = tid + k*256;
        if (oi >= HH*WF) break;
        int h = oi/WF, f = oi - h*WF;
        float re=0.f, im=0.f;
        int idx = 0;
        for (int w=0;w<WW;w++){
            float v = plane[h][w];
            re += v*ct[idx]; im -= v*st[idx];
            idx = (idx + f) & 63;
        }
        xfr[oi] = re; xfi[oi] = im;
    }
}

// ---- K7: sequential scan over L with R complex states in registers,
//          fused with collapsed mix/proj -> yfreq ----
__global__ void k_scan(float* __restrict__ ws){
    __shared__ float wv[66];
    int tid = threadIdx.x;
    if (tid < 66) wv[tid] = ws[OFF_WVEC + tid];
    __syncthreads();
    int t = blockIdx.x*256 + tid;
    if (t >= CC*HH*WF) return;
    int f = t % WF;
    int c = t / (HH*WF);
    float sre[RR], sim[RR];
    #pragma unroll
    for (int r=0;r<RR;r++){ sre[r]=0.f; sim[r]=0.f; }
    for (int l=0;l<LL;l++){
        int base = ((l*CC+c)*WF+f)*RR;
        const float4* A4 = reinterpret_cast<const float4*>(ws + OFF_ARE + base);
        const float4* I4 = reinterpret_cast<const float4*>(ws + OFF_AIM + base);
        const float4* S4 = reinterpret_cast<const float4*>(ws + OFF_SGG + base);
        float ar[RR], ai[RR], sg[RR];
        #pragma unroll
        for (int q=0;q<4;q++){
            float4 a = A4[q], bb = I4[q], s = S4[q];
            ar[4*q]=a.x; ar[4*q+1]=a.y; ar[4*q+2]=a.z; ar[4*q+3]=a.w;
            ai[4*q]=bb.x; ai[4*q+1]=bb.y; ai[4*q+2]=bb.z; ai[4*q+3]=bb.w;
            sg[4*q]=s.x; sg[4*q+1]=s.y; sg[4*q+2]=s.z; sg[4*q+3]=s.w;
        }
        float xr = ws[OFF_XFR + l*(CC*HH*WF) + t];
        float xi = ws[OFF_XFI + l*(CC*HH*WF) + t];
        float yr = wv[64], yi = wv[65];
        #pragma unroll
        for (int r=0;r<RR;r++){
            float nre = ar[r]*sre[r] - ai[r]*sim[r] + sg[r]*xr;
            float nim = ar[r]*sim[r] + ai[r]*sre[r] + sg[r]*xi;
            sre[r]=nre; sim[r]=nim;
            yr += wv[r]*nre + wv[16+r]*nim;
            yi += wv[32+r]*nre + wv[48+r]*nim;
        }
        ws[OFF_YFR + l*(CC*HH*WF) + t] = yr;
        ws[OFF_YFI + l*(CC*HH*WF) + t] = yi;
    }
}

// ---- K8: irfft (direct inverse DFT, n=64). Block = (l,c). ----
__global__ void k_irfft(float* __restrict__ ws){
    __shared__ float yr[HH][WF], yi[HH][WF];
    __shared__ float ct[64], st[64];
    int b = blockIdx.x; int l = b>>5, c = b&31;
    int tid = threadIdx.x;
    if (tid < 64){ float ang = 2.f*PI_F*(float)tid/64.f; ct[tid]=cosf(ang); st[tid]=sinf(ang); }
    const float* Yr = ws + OFF_YFR + (l*CC+c)*HH*WF;
    const float* Yi = ws + OFF_YFI + (l*CC+c)*HH*WF;
    for (int k=0;k<9;k++){
        int i = tid + k*256;
        if (i < HH*WF){ int h=i/WF, f=i-h*WF; yr[h][f]=Yr[i]; yi[h][f]=Yi[i]; }
    }
    __syncthreads();
    float* y1 = ws + OFF_Y1 + (l*CC+c)*HH*WW;
    for (int k=0;k<16;k++){
        int pix = tid + k*256;
        int h = pix>>6, w = pix&63;
        float acc = yr[h][0] + ((w&1)? -yr[h][32] : yr[h][32]);
        #pragma unroll
        for (int f=1;f<32;f++){
            int a = (f*w)&63;
            acc += 2.0f*(yr[h][f]*ct[a] - yi[h][f]*st[a]);
        }
        y1[pix] = acc*(1.0f/64.0f);
    }
}

// ---- K9: pif channel mix (32x32 per pixel). Block = (l,h). ----
__global__ void k_pif(const float* __restrict__ pw, const float* __restrict__ pb,
                      float* __restrict__ ws){
    __shared__ float row[CC][WW];
    int b = blockIdx.x; int l = b>>6, h = b&63;
    int tid = threadIdx.x;
    for (int k=0;k<8;k++){
        int i = tid + k*256;
        int ci = i>>6, w = i&63;
        row[ci][w] = ws[OFF_Y1 + ((l*CC+ci)*HH + h)*WW + w];
    }
    __syncthreads();
    for (int k=0;k<8;k++){
        int i = tid + k*256;
        int o = i>>6, w = i&63;
        float acc = pb[o];
        #pragma unroll
        for (int ci=0;ci<CC;ci++) acc += pw[o*CC+ci]*row[ci][w];
        ws[OFF_Y2 + ((l*CC+o)*HH + h)*WW + w] = acc;
    }
}

// ---- K10: GroupNorm stats per (l, group) ----
__global__ void k_gnstat(float* __restrict__ ws){
    __shared__ float rs[256], rq[256];
    int b = blockIdx.x; int l = b>>2, g = b&3;
    const float* z = ws + OFF_Y2 + (l*CC + g*8)*HH*WW;
    int tid = threadIdx.x;
    float s=0.f, q=0.f;
    for (int i=tid;i<8*HH*WW;i+=256){ float v=z[i]; s+=v; q+=v*v; }
    rs[tid]=s; rq[tid]=q; __syncthreads();
    for (int off=128; off>0; off>>=1){
        if (tid<off){ rs[tid]+=rs[tid+off]; rq[tid]+=rq[tid+off]; }
        __syncthreads();
    }
    if (tid==0){
        float mean = rs[0]/32768.0f;
        float var = rq[0]/32768.0f - mean*mean;
        ws[OFF_GNM + b] = mean;
        ws[OFF_GNR + b] = rsqrtf(var + 1e-5f);
    }
}

// ---- K11: normalize (in place) + W-mean -> ym[l][h][c]. Block = (l,c). ----
__global__ void k_normym(const float* __restrict__ gn_w, const float* __restrict__ gn_b,
                         float* __restrict__ ws){
    int b = blockIdx.x; int l = b>>5, c = b&31;
    int tid = threadIdx.x;
    int g = c>>3;
    float mu = ws[OFF_GNM + l*4+g], rstd = ws[OFF_GNR + l*4+g];
    float gw = gn_w[c], gb = gn_b[c];
    float* z = ws + OFF_Y2 + (l*CC+c)*HH*WW;
    int w = tid&63, hs = tid>>6;
    for (int k=0;k<16;k++){
        int h = hs*16 + k;
        int i = h*WW + w;
        float v = (z[i]-mu)*rstd*gw + gb;
        z[i] = v;
        float s = v;
        for (int off=32; off>0; off>>=1) s += __shfl_down(s, off, 64);
        if ((tid&63)==0) ws[OFF_YM + (l*HH+h)*CC + c] = s*(1.0f/64.0f);
    }
}

// ---- K12: gate MLP per (l,h,c) ----
__global__ void k_gate(const float* __restrict__ g1w, const float* __restrict__ g1b,
                       const float* __restrict__ g2w, const float* __restrict__ g2b,
                       float* __restrict__ ws){
    int t = blockIdx.x*256 + threadIdx.x;
    if (t >= LL*HH*CC) return;
    int c = t & 31, h = (t>>5)&63, l = t>>11;
    const float* ym = ws + OFF_YM + (l*HH+h)*CC;
    float mid[4];
    #pragma unroll
    for (int m=0;m<4;m++){
        float a = g1b[m];
        for (int i=0;i<CC;i++) a += ym[i]*g1w[m*CC+i];
        mid[m] = a*sigmoidf_(a);
    }
    float a = g2b[c];
    #pragma unroll
    for (int m=0;m<4;m++) a += mid[m]*g2w[c*4+m];
    ws[OFF_GATE + t] = sigmoidf_(a);
}

// ---- K13: residual: out = x + z*gate ----
__global__ void k_final(const float* __restrict__ x, float* __restrict__ out,
                        const float* __restrict__ ws){
    int t = blockIdx.x*256 + threadIdx.x;
    int w = t&63, h = (t>>6)&63, l = (t>>12)&15, c = t>>16;
    float z = ws[OFF_Y2 + ((l*CC+c)*HH+h)*WW + w];
    float gt = ws[OFF_GATE + (l*HH+h)*CC + c];
    out[t] = x[t] + z*gt;
}

extern "C" void kernel_launch(void* const* d_in, const int* in_sizes, int n_in,
                              void* d_out, int out_size, void* d_ws, size_t ws_size,
                              hipStream_t stream){
    const float* x    = (const float*)d_in[0];
    const float* dt   = (const float*)d_in[1];
    const float* c1w  = (const float*)d_in[2];
    const float* c1b  = (const float*)d_in[3];
    const float* c2w  = (const float*)d_in[4];
    const float* c2b  = (const float*)d_in[5];
    const float* gfcw = (const float*)d_in[6];
    const float* gfcb = (const float*)d_in[7];
    const float* hw   = (const float*)d_in[8];
    const float* hb   = (const float*)d_in[9];
    const float* mixw = (const float*)d_in[10];
    const float* mixb = (const float*)d_in[11];
    const float* rs   = (const float*)d_in[12];
    const float* pjw  = (const float*)d_in[13];
    const float* pjb  = (const float*)d_in[14];
    const float* pifw = (const float*)d_in[15];
    const float* pifb = (const float*)d_in[16];
    const float* gnw  = (const float*)d_in[17];
    const float* gnb  = (const float*)d_in[18];
    const float* g1w  = (const float*)d_in[19];
    const float* g1b  = (const float*)d_in[20];
    const float* g2w  = (const float*)d_in[21];
    const float* g2b  = (const float*)d_in[22];
    float* ws  = (float*)d_ws;
    float* out = (float*)d_out;

    k_prep  <<<1,    64,  0, stream>>>(mixw, mixb, rs, pjw, pjb, ws);
    k_conv1 <<<512,  256, 0, stream>>>(x, c1w, c1b, ws);
    k_conv2 <<<512,  256, 0, stream>>>(c2w, c2b, ws);
    k_glob  <<<2,    256, 0, stream>>>(gfcw, gfcb, ws);
    k_feat  <<<66,   256, 0, stream>>>(ws);
    k_head  <<<1056, 256, 0, stream>>>(hw, hb, dt, ws);
    k_rfft  <<<512,  256, 0, stream>>>(x, ws);
    k_scan  <<<264,  256, 0, stream>>>(ws);
    k_irfft <<<512,  256, 0, stream>>>(ws);
    k_pif   <<<1024, 256, 0, stream>>>(pifw, pifb, ws);
    k_gnstat<<<64,   256, 0, stream>>>(ws);
    k_normym<<<512,  256, 0, stream>>>(gnw, gnb, ws);
    k_gate  <<<128,  256, 0, stream>>>(g1w, g1b, g2w, g2b, ws);
    k_final <<<8192, 256, 0, stream>>>(x, out, ws);
}

// Round 2
// 640.861 us; speedup vs baseline: 2.1020x; 2.1020x over previous
//
#include <hip/hip_runtime.h>
#include <math.h>

#define CC 32
#define LL 16
#define HH 64
#define WW 64
#define WF 33
#define RR 16
#define PI_F 3.14159265358979323846f

// ---- workspace layout (floats). Regions reused across phases. ----
#define OFF_F1      0          // 2097152  f1 (conv1 out); later reused as Y2
#define OFF_COLSUM  2097152    // 32768    [l][c][w] column sums of silu(conv2)
#define OFF_GSUM    2129920    // 512      [l][c] total sums
#define OFF_GLOB    2130432    // 512
#define OFF_FEAT    2130944    // 16896    [l][wf][c]
#define OFF_ARE     2147840    // 270336   [l][c][wf][r]
#define OFF_AIM     2418176    // 270336
#define OFF_SGG     2688512    // 270336
#define OFF_XFR     2958848    // 1081344  [l][c][h][f]
#define OFF_XFI     4040192    // 1081344
#define OFF_YFR     5121536    // 1081344
#define OFF_YFI     6202880    // 1081344
#define OFF_Y1      2958848    // 2097152  irfft out (overlaps dead XFR/XFI)
#define OFF_Y2      0          // 2097152  pif out / z (overlaps dead F1)
#define OFF_GNM     7284224    // 64
#define OFF_GNR     7284288    // 64
#define OFF_YM      7284352    // 32768    [l][h][c]
#define OFF_GATE    7317120    // 32768
#define OFF_WVEC    7349888    // 66
// total ~29.4 MB

__device__ __forceinline__ float sigmoidf_(float x){ return 1.0f/(1.0f+expf(-x)); }

// ---- K0: collapse mix/rank_scale/proj into two 32-vectors ----
__global__ void k_prep(const float* __restrict__ mix_w, const float* __restrict__ mix_b,
                       const float* __restrict__ rank_scale, const float* __restrict__ proj_w,
                       const float* __restrict__ proj_b, float* __restrict__ ws){
    float* wv = ws + OFF_WVEC;
    int t = threadIdx.x;
    if (t < 32){
        float sre=0.f, sim=0.f;
        for (int r=0;r<RR;r++){
            float a = proj_w[r]*rank_scale[r];
            sre += a*mix_w[r*2*RR + t];
            sim += a*mix_w[(RR+r)*2*RR + t];
        }
        wv[t] = sre;
        wv[32+t] = sim;
    }
    if (t == 0){
        float cre=0.f, cim=0.f;
        for (int r=0;r<RR;r++){
            float a = proj_w[r]*rank_scale[r];
            cre += a*mix_b[r];
            cim += a*mix_b[RR+r];
        }
        wv[64] = cre + proj_b[0];
        wv[65] = cim;
    }
}

// ---- K1/K2: 3x3 SAME conv (32->32) + SiLU, LDS-staged, register-blocked.
// MODE 0: src=x (global), write silu to f1.
// MODE 1: src=f1 (ws), reduce silu to colsum[l][c][w] (atomicAdd) + gsum[l][c].
// Block: (l, htile of 2 rows). 128 threads = cg(4 co-groups of 8) x wq(16 w-quads of 4) x row(2).
template<int MODE>
__global__ __launch_bounds__(128) void k_conv(const float* __restrict__ src, long ci_stride, long l_stride,
                                              const float* __restrict__ cw, const float* __restrict__ cb,
                                              float* __restrict__ ws){
    __shared__ float xs[8][4][65];      // 8-ci chunk, rows h0-1..h0+2, padded
    __shared__ float lw[CC*9*CC];       // [(ci*9+k)*32 + co]  36KB
    __shared__ float red[MODE ? CC*WW : 1];

    const int tid = threadIdx.x;
    const int b   = blockIdx.x;
    const int l   = b >> 5;
    const int ht  = b & 31;
    const int h0  = ht*2;

    const int wq  = tid & 15;
    const int row = (tid >> 4) & 1;
    const int cg  = tid >> 5;
    const int w0  = wq*4;
    const int co0 = cg*8;

    // load transposed weights
    for (int i = tid; i < CC*9*CC; i += 128){
        int co = i & 31, rem = i >> 5;
        lw[i] = cw[co*288 + rem];
    }
    if (MODE){
        for (int i = tid; i < CC*WW; i += 128) red[i] = 0.f;
    }

    float acc[8][4];
    #pragma unroll
    for (int i=0;i<8;i++)
        #pragma unroll
        for (int j=0;j<4;j++) acc[i][j]=0.f;

    const float* sbase = src + (long)l*l_stride;

    for (int chunk = 0; chunk < 4; ++chunk){
        __syncthreads();
        // load 8ci x 4rows x 64w
        for (int i = tid; i < 2048; i += 128){
            int cil = i >> 8, rr = (i >> 6) & 3, w = i & 63;
            int h = h0 - 1 + rr;
            float v = 0.f;
            if (h >= 0 && h < HH) v = sbase[(long)(chunk*8+cil)*ci_stride + h*WW + w];
            xs[cil][rr][w] = v;
        }
        __syncthreads();
        #pragma unroll
        for (int cil = 0; cil < 8; ++cil){
            const int cig = chunk*8 + cil;
            #pragma unroll
            for (int kh = 0; kh < 3; ++kh){
                const float* xr = &xs[cil][row+kh][0];
                float xv[6];
                #pragma unroll
                for (int j = 0; j < 6; ++j){
                    int wi = w0 - 1 + j;
                    xv[j] = (wi >= 0 && wi < WW) ? xr[wi] : 0.f;
                }
                const float* wp = &lw[(cig*9 + kh*3)*32 + co0];
                #pragma unroll
                for (int kw = 0; kw < 3; ++kw){
                    float4 wa = *(const float4*)(wp + kw*32);
                    float4 wb = *(const float4*)(wp + kw*32 + 4);
                    #pragma unroll
                    for (int j = 0; j < 4; ++j){
                        float xvv = xv[j+kw];
                        acc[0][j] += xvv*wa.x; acc[1][j] += xvv*wa.y;
                        acc[2][j] += xvv*wa.z; acc[3][j] += xvv*wa.w;
                        acc[4][j] += xvv*wb.x; acc[5][j] += xvv*wb.y;
                        acc[6][j] += xvv*wb.z; acc[7][j] += xvv*wb.w;
                    }
                }
            }
        }
    }

    if (MODE == 0){
        const int h = h0 + row;
        float* dst = ws + OFF_F1 + ((long)l*CC)*HH*WW + h*WW + w0;
        #pragma unroll
        for (int i = 0; i < 8; ++i){
            float bias = cb[co0+i];
            float4 o;
            float a0 = acc[i][0]+bias, a1 = acc[i][1]+bias, a2 = acc[i][2]+bias, a3 = acc[i][3]+bias;
            o.x = a0*sigmoidf_(a0); o.y = a1*sigmoidf_(a1);
            o.z = a2*sigmoidf_(a2); o.w = a3*sigmoidf_(a3);
            *(float4*)(dst + (long)(co0+i)*HH*WW) = o;
        }
    } else {
        __syncthreads();
        #pragma unroll
        for (int i = 0; i < 8; ++i){
            float bias = cb[co0+i];
            #pragma unroll
            for (int j = 0; j < 4; ++j){
                float a = acc[i][j] + bias;
                a = a*sigmoidf_(a);
                atomicAdd(&red[(co0+i)*WW + w0 + j], a);
            }
        }
        __syncthreads();
        // 2048 values, 128 threads: t -> co = t>>2, wseg = (t&3)*16
        int co = tid >> 2, wseg = (tid & 3)*16;
        float s = 0.f;
        #pragma unroll
        for (int j = 0; j < 16; ++j){
            float v = red[co*WW + wseg + j];
            s += v;
            atomicAdd(&ws[OFF_COLSUM + (l*CC+co)*WW + wseg + j], v);
        }
        s += __shfl_down(s, 2, 4);
        s += __shfl_down(s, 1, 4);
        if ((tid & 3) == 0) atomicAdd(&ws[OFF_GSUM + l*CC + co], s);
    }
}

// ---- K3: glob = sigmoid(mean @ gfc_w.T + b) ----
__global__ void k_glob(const float* __restrict__ gfc_w, const float* __restrict__ gfc_b,
                       float* __restrict__ ws){
    int t = blockIdx.x*blockDim.x + threadIdx.x;
    if (t >= LL*CC) return;
    int l = t >> 5, o = t & 31;
    const float* gs = ws + OFF_GSUM + l*CC;
    float acc = gfc_b[o];
    for (int i=0;i<CC;i++) acc += gs[i]*(1.0f/4096.0f)*gfc_w[o*CC+i];
    ws[OFF_GLOB + t] = sigmoidf_(acc);
}

// ---- K4: adaptive avg pool over W (64->33), times glob ----
__global__ void k_feat(float* __restrict__ ws){
    int t = blockIdx.x*blockDim.x + threadIdx.x;
    if (t >= LL*WF*CC) return;
    int c = t & 31;
    int lw_ = t >> 5;
    int wf = lw_ % WF, l = lw_ / WF;
    int s = (wf*64)/33;
    int e = ((wf+1)*64 + 32)/33;
    const float* cs = ws + OFF_COLSUM + (l*CC+c)*WW;
    float sum = 0.f;
    for (int w=s;w<e;w++) sum += cs[w];
    ws[OFF_FEAT + (l*WF+wf)*CC + c] = ws[OFF_GLOB + l*CC + c] * sum / (64.0f*(float)(e-s));
}

// ---- K5: head matmul + activations ----
__global__ void k_head(const float* __restrict__ hw, const float* __restrict__ hb,
                       const float* __restrict__ dt, float* __restrict__ ws){
    int t = blockIdx.x*blockDim.x + threadIdx.x;
    if (t >= LL*WF*CC*RR) return;
    int r = t & 15, c = (t>>4) & 31;
    int lw_ = t >> 9;
    int wf = lw_ % WF, l = lw_ / WF;
    const float* feat = ws + OFF_FEAT + (l*WF+wf)*CC;
    int j0 = (c*RR + r)*3;
    const float* w0 = hw + j0*CC;
    float p0=hb[j0], p1=hb[j0+1], p2=hb[j0+2];
    for (int i=0;i<CC;i++){
        float fv = feat[i];
        p0 += fv*w0[i]; p1 += fv*w0[CC+i]; p2 += fv*w0[2*CC+i];
    }
    float nu = fmaxf(p0,0.f) + log1pf(expf(-fabsf(p0)));
    float th = tanhf(p1)*PI_F;
    float sg = sigmoidf_(p2);
    float dtv = dt[l];
    float decay = expf(-nu*dtv);
    float ang = th*dtv;
    float g = 1.0f - expf(-2.0f*fmaxf(dtv,0.f));
    int idx = ((l*CC+c)*WF+wf)*RR + r;
    ws[OFF_ARE+idx] = decay*cosf(ang);
    ws[OFF_AIM+idx] = decay*sinf(ang);
    ws[OFF_SGG+idx] = sg*g;
}

// ---- K6: rfft over W (direct DFT). Block = (l,c). ----
__global__ void k_rfft(const float* __restrict__ x, float* __restrict__ ws){
    __shared__ float plane[HH][WW+1];
    __shared__ float ct[64], st[64];
    int b = blockIdx.x; int l = b >> 5, c = b & 31;
    int tid = threadIdx.x;
    if (tid < 64){
        float ang = 2.0f*PI_F*(float)tid/64.0f;
        ct[tid] = cosf(ang); st[tid] = sinf(ang);
    }
    const float* xp = x + (c*LL + l)*HH*WW;
    for (int k=0;k<16;k++){
        int pix = tid + k*256;
        plane[pix>>6][pix&63] = xp[pix];
    }
    __syncthreads();
    float* xfr = ws + OFF_XFR + (l*CC + c)*HH*WF;
    float* xfi = ws + OFF_XFI + (l*CC + c)*HH*WF;
    for (int k=0;k<9;k++){
        int oi = tid + k*256;
        if (oi >= HH*WF) break;
        int h = oi/WF, f = oi - h*WF;
        float re=0.f, im=0.f;
        int idx = 0;
        for (int w=0;w<WW;w++){
            float v = plane[h][w];
            re += v*ct[idx]; im -= v*st[idx];
            idx = (idx + f) & 63;
        }
        xfr[oi] = re; xfi[oi] = im;
    }
}

// ---- K7: sequential scan over L, fused collapsed mix/proj ----
__global__ void k_scan(float* __restrict__ ws){
    __shared__ float wv[66];
    int tid = threadIdx.x;
    if (tid < 66) wv[tid] = ws[OFF_WVEC + tid];
    __syncthreads();
    int t = blockIdx.x*256 + tid;
    if (t >= CC*HH*WF) return;
    int f = t % WF;
    int c = t / (HH*WF);
    float sre[RR], sim[RR];
    #pragma unroll
    for (int r=0;r<RR;r++){ sre[r]=0.f; sim[r]=0.f; }
    for (int l=0;l<LL;l++){
        int base = ((l*CC+c)*WF+f)*RR;
        const float4* A4 = reinterpret_cast<const float4*>(ws + OFF_ARE + base);
        const float4* I4 = reinterpret_cast<const float4*>(ws + OFF_AIM + base);
        const float4* S4 = reinterpret_cast<const float4*>(ws + OFF_SGG + base);
        float ar[RR], ai[RR], sg[RR];
        #pragma unroll
        for (int q=0;q<4;q++){
            float4 a = A4[q], bb = I4[q], s = S4[q];
            ar[4*q]=a.x; ar[4*q+1]=a.y; ar[4*q+2]=a.z; ar[4*q+3]=a.w;
            ai[4*q]=bb.x; ai[4*q+1]=bb.y; ai[4*q+2]=bb.z; ai[4*q+3]=bb.w;
            sg[4*q]=s.x; sg[4*q+1]=s.y; sg[4*q+2]=s.z; sg[4*q+3]=s.w;
        }
        float xr = ws[OFF_XFR + l*(CC*HH*WF) + t];
        float xi = ws[OFF_XFI + l*(CC*HH*WF) + t];
        float yr = wv[64], yi = wv[65];
        #pragma unroll
        for (int r=0;r<RR;r++){
            float nre = ar[r]*sre[r] - ai[r]*sim[r] + sg[r]*xr;
            float nim = ar[r]*sim[r] + ai[r]*sre[r] + sg[r]*xi;
            sre[r]=nre; sim[r]=nim;
            yr += wv[r]*nre + wv[16+r]*nim;
            yi += wv[32+r]*nre + wv[48+r]*nim;
        }
        ws[OFF_YFR + l*(CC*HH*WF) + t] = yr;
        ws[OFF_YFI + l*(CC*HH*WF) + t] = yi;
    }
}

// ---- K8: irfft (direct inverse DFT, n=64). Block = (l,c). ----
__global__ void k_irfft(float* __restrict__ ws){
    __shared__ float yr[HH][WF], yi[HH][WF];
    __shared__ float ct[64], st[64];
    int b = blockIdx.x; int l = b>>5, c = b&31;
    int tid = threadIdx.x;
    if (tid < 64){ float ang = 2.f*PI_F*(float)tid/64.f; ct[tid]=cosf(ang); st[tid]=sinf(ang); }
    const float* Yr = ws + OFF_YFR + (l*CC+c)*HH*WF;
    const float* Yi = ws + OFF_YFI + (l*CC+c)*HH*WF;
    for (int k=0;k<9;k++){
        int i = tid + k*256;
        if (i < HH*WF){ int h=i/WF, f=i-h*WF; yr[h][f]=Yr[i]; yi[h][f]=Yi[i]; }
    }
    __syncthreads();
    float* y1 = ws + OFF_Y1 + (l*CC+c)*HH*WW;
    for (int k=0;k<16;k++){
        int pix = tid + k*256;
        int h = pix>>6, w = pix&63;
        float acc = yr[h][0] + ((w&1)? -yr[h][32] : yr[h][32]);
        #pragma unroll
        for (int f=1;f<32;f++){
            int a = (f*w)&63;
            acc += 2.0f*(yr[h][f]*ct[a] - yi[h][f]*st[a]);
        }
        y1[pix] = acc*(1.0f/64.0f);
    }
}

// ---- K9: pif channel mix ----
__global__ void k_pif(const float* __restrict__ pw, const float* __restrict__ pb,
                      float* __restrict__ ws){
    __shared__ float row[CC][WW];
    int b = blockIdx.x; int l = b>>6, h = b&63;
    int tid = threadIdx.x;
    for (int k=0;k<8;k++){
        int i = tid + k*256;
        int ci = i>>6, w = i&63;
        row[ci][w] = ws[OFF_Y1 + ((l*CC+ci)*HH + h)*WW + w];
    }
    __syncthreads();
    for (int k=0;k<8;k++){
        int i = tid + k*256;
        int o = i>>6, w = i&63;
        float acc = pb[o];
        #pragma unroll
        for (int ci=0;ci<CC;ci++) acc += pw[o*CC+ci]*row[ci][w];
        ws[OFF_Y2 + ((l*CC+o)*HH + h)*WW + w] = acc;
    }
}

// ---- K10: GroupNorm stats ----
__global__ void k_gnstat(float* __restrict__ ws){
    __shared__ float rs[256], rq[256];
    int b = blockIdx.x; int l = b>>2, g = b&3;
    const float* z = ws + OFF_Y2 + (l*CC + g*8)*HH*WW;
    int tid = threadIdx.x;
    float s=0.f, q=0.f;
    for (int i=tid;i<8*HH*WW;i+=256){ float v=z[i]; s+=v; q+=v*v; }
    rs[tid]=s; rq[tid]=q; __syncthreads();
    for (int off=128; off>0; off>>=1){
        if (tid<off){ rs[tid]+=rs[tid+off]; rq[tid]+=rq[tid+off]; }
        __syncthreads();
    }
    if (tid==0){
        float mean = rs[0]/32768.0f;
        float var = rq[0]/32768.0f - mean*mean;
        ws[OFF_GNM + b] = mean;
        ws[OFF_GNR + b] = rsqrtf(var + 1e-5f);
    }
}

// ---- K11: normalize + W-mean ----
__global__ void k_normym(const float* __restrict__ gn_w, const float* __restrict__ gn_b,
                         float* __restrict__ ws){
    int b = blockIdx.x; int l = b>>5, c = b&31;
    int tid = threadIdx.x;
    int g = c>>3;
    float mu = ws[OFF_GNM + l*4+g], rstd = ws[OFF_GNR + l*4+g];
    float gw = gn_w[c], gb = gn_b[c];
    float* z = ws + OFF_Y2 + (l*CC+c)*HH*WW;
    int w = tid&63, hs = tid>>6;
    for (int k=0;k<16;k++){
        int h = hs*16 + k;
        int i = h*WW + w;
        float v = (z[i]-mu)*rstd*gw + gb;
        z[i] = v;
        float s = v;
        for (int off=32; off>0; off>>=1) s += __shfl_down(s, off, 64);
        if ((tid&63)==0) ws[OFF_YM + (l*HH+h)*CC + c] = s*(1.0f/64.0f);
    }
}

// ---- K12: gate MLP ----
__global__ void k_gate(const float* __restrict__ g1w, const float* __restrict__ g1b,
                       const float* __restrict__ g2w, const float* __restrict__ g2b,
                       float* __restrict__ ws){
    int t = blockIdx.x*256 + threadIdx.x;
    if (t >= LL*HH*CC) return;
    int c = t & 31, h = (t>>5)&63, l = t>>11;
    const float* ym = ws + OFF_YM + (l*HH+h)*CC;
    float mid[4];
    #pragma unroll
    for (int m=0;m<4;m++){
        float a = g1b[m];
        for (int i=0;i<CC;i++) a += ym[i]*g1w[m*CC+i];
        mid[m] = a*sigmoidf_(a);
    }
    float a = g2b[c];
    #pragma unroll
    for (int m=0;m<4;m++) a += mid[m]*g2w[c*4+m];
    ws[OFF_GATE + t] = sigmoidf_(a);
}

// ---- K13: residual ----
__global__ void k_final(const float* __restrict__ x, float* __restrict__ out,
                        const float* __restrict__ ws){
    int t = blockIdx.x*256 + threadIdx.x;
    int w = t&63, h = (t>>6)&63, l = (t>>12)&15, c = t>>16;
    float z = ws[OFF_Y2 + ((l*CC+c)*HH+h)*WW + w];
    float gt = ws[OFF_GATE + (l*HH+h)*CC + c];
    out[t] = x[t] + z*gt;
}

extern "C" void kernel_launch(void* const* d_in, const int* in_sizes, int n_in,
                              void* d_out, int out_size, void* d_ws, size_t ws_size,
                              hipStream_t stream){
    const float* x    = (const float*)d_in[0];
    const float* dt   = (const float*)d_in[1];
    const float* c1w  = (const float*)d_in[2];
    const float* c1b  = (const float*)d_in[3];
    const float* c2w  = (const float*)d_in[4];
    const float* c2b  = (const float*)d_in[5];
    const float* gfcw = (const float*)d_in[6];
    const float* gfcb = (const float*)d_in[7];
    const float* hw   = (const float*)d_in[8];
    const float* hb   = (const float*)d_in[9];
    const float* mixw = (const float*)d_in[10];
    const float* mixb = (const float*)d_in[11];
    const float* rs   = (const float*)d_in[12];
    const float* pjw  = (const float*)d_in[13];
    const float* pjb  = (const float*)d_in[14];
    const float* pifw = (const float*)d_in[15];
    const float* pifb = (const float*)d_in[16];
    const float* gnw  = (const float*)d_in[17];
    const float* gnb  = (const float*)d_in[18];
    const float* g1w  = (const float*)d_in[19];
    const float* g1b  = (const float*)d_in[20];
    const float* g2w  = (const float*)d_in[21];
    const float* g2b  = (const float*)d_in[22];
    float* ws  = (float*)d_ws;
    float* out = (float*)d_out;

    k_prep  <<<1,    64,  0, stream>>>(mixw, mixb, rs, pjw, pjb, ws);
    // conv1: src = x, layout [C][L][H][W] -> ci stride 16*4096, l stride 4096
    k_conv<0><<<512, 128, 0, stream>>>(x, (long)LL*HH*WW, (long)HH*WW, c1w, c1b, ws);
    // zero colsum+gsum before conv2's atomics
    hipMemsetAsync((void*)(ws + OFF_COLSUM), 0, (32768+512)*sizeof(float), stream);
    // conv2: src = f1 in ws, layout [L][C][H][W] -> ci stride 4096, l stride 32*4096
    k_conv<1><<<512, 128, 0, stream>>>(ws + OFF_F1, (long)HH*WW, (long)CC*HH*WW, c2w, c2b, ws);
    k_glob  <<<2,    256, 0, stream>>>(gfcw, gfcb, ws);
    k_feat  <<<66,   256, 0, stream>>>(ws);
    k_head  <<<1056, 256, 0, stream>>>(hw, hb, dt, ws);
    k_rfft  <<<512,  256, 0, stream>>>(x, ws);
    k_scan  <<<264,  256, 0, stream>>>(ws);
    k_irfft <<<512,  256, 0, stream>>>(ws);
    k_pif   <<<1024, 256, 0, stream>>>(pifw, pifb, ws);
    k_gnstat<<<64,   256, 0, stream>>>(ws);
    k_normym<<<512,  256, 0, stream>>>(gnw, gnb, ws);
    k_gate  <<<128,  256, 0, stream>>>(g1w, g1b, g2w, g2b, ws);
    k_final <<<8192, 256, 0, stream>>>(x, out, ws);
}

// Round 3
// 384.509 us; speedup vs baseline: 3.5035x; 1.6667x over previous
//
#include <hip/hip_runtime.h>
#include <math.h>

#define CC 32
#define LL 16
#define HH 64
#define WW 64
#define WF 33
#define RR 16
#define PI_F 3.14159265358979323846f

// ---- workspace layout (floats). Regions reused across phases. ----
#define OFF_F1      0          // 2097152  f1 (conv1 out); later reused as Y2
#define OFF_COLSUM  2097152    // 32768    [l][c][w]
#define OFF_GSUM    2129920    // 512
#define OFF_GLOB    2130432    // 512
#define OFF_FEAT    2130944    // 16896    [l][wf][c]
#define OFF_ARE     2147840    // 270336   [l][c][wf][r]
#define OFF_AIM     2418176    // 270336
#define OFF_SGG     2688512    // 270336
#define OFF_XFR     2958848    // 1081344  [l][c][h][f]
#define OFF_XFI     4040192    // 1081344
#define OFF_YFR     5121536    // 1081344
#define OFF_YFI     6202880    // 1081344
#define OFF_Y1      2958848    // 2097152  (overlaps dead XFR/XFI)
#define OFF_Y2      0          // 2097152  (overlaps dead F1)
#define OFF_GNM     7284224    // 64
#define OFF_GNR     7284288    // 64
#define OFF_YM      7284352    // 32768    [l][h][c]
#define OFF_GATE    7317120    // 32768
#define OFF_WVEC    7349888    // 66
// total ~29.4 MB

__device__ __forceinline__ float sigmoidf_(float x){ return 1.0f/(1.0f+expf(-x)); }

// ---- K0: collapse mix/rank_scale/proj into two 32-vectors ----
__global__ void k_prep(const float* __restrict__ mix_w, const float* __restrict__ mix_b,
                       const float* __restrict__ rank_scale, const float* __restrict__ proj_w,
                       const float* __restrict__ proj_b, float* __restrict__ ws){
    float* wv = ws + OFF_WVEC;
    int t = threadIdx.x;
    if (t < 32){
        float sre=0.f, sim=0.f;
        for (int r=0;r<RR;r++){
            float a = proj_w[r]*rank_scale[r];
            sre += a*mix_w[r*2*RR + t];
            sim += a*mix_w[(RR+r)*2*RR + t];
        }
        wv[t] = sre;
        wv[32+t] = sim;
    }
    if (t == 0){
        float cre=0.f, cim=0.f;
        for (int r=0;r<RR;r++){
            float a = proj_w[r]*rank_scale[r];
            cre += a*mix_b[r];
            cim += a*mix_b[RR+r];
        }
        wv[64] = cre + proj_b[0];
        wv[65] = cim;
    }
}

// ---- K1/K2: 3x3 SAME conv (32->32) + SiLU, LDS-staged, register-blocked.
// MODE 0: src=x, write silu to f1.  MODE 1: src=f1, reduce to colsum/gsum.
// Block = (l, h-tile of 2 rows). 256 thr = 16 wq(4w) x 2 row x 8 cg(4co).
// acc[4co][4w] = 16 VGPR. Spill-proofing: launch_bounds cap + unroll 1 on
// the chunk loop so no cross-barrier global-load hoisting.
template<int MODE>
__global__ __launch_bounds__(256, 2) void k_conv(const float* __restrict__ src,
                                                 long ci_stride, long l_stride,
                                                 const float* __restrict__ cw, const float* __restrict__ cb,
                                                 float* __restrict__ ws){
    __shared__ float xs[8][4][66];      // halo cols [0] and [65] zeroed; interior at [1+w]
    __shared__ float lw[9*CC*CC];       // [(ci*9+tap)*32 + co]  36 KB
    __shared__ float red[MODE ? CC*WW : 1];

    const int tid = threadIdx.x;
    const int l   = blockIdx.x >> 5;
    const int h0  = (blockIdx.x & 31)*2;

    const int wq  = tid & 15;
    const int row = (tid >> 4) & 1;
    const int cg  = tid >> 5;
    const int w0  = wq*4;
    const int co0 = cg*4;

    // transposed weight stage (coalesced-ish global read, scattered ds_write)
    #pragma unroll 4
    for (int i = tid; i < CC*9*CC; i += 256){
        int co = i >> 8, rem = i & 255;        // 288 per co: handle remainder below
        (void)co; (void)rem;
        int coo = i / 288, rr = i - coo*288;
        lw[rr*32 + coo] = cw[i];
    }
    if (MODE){
        #pragma unroll 1
        for (int i = tid; i < CC*WW; i += 256) red[i] = 0.f;
    }

    float acc[4][4];
    #pragma unroll
    for (int i=0;i<4;i++)
        #pragma unroll
        for (int j=0;j<4;j++) acc[i][j]=0.f;

    const float* sbase = src + (long)l*l_stride;

    #pragma unroll 1
    for (int chunk = 0; chunk < 4; ++chunk){
        __syncthreads();
        // zero halo columns (64 entries)
        if (tid < 64){
            int cil = tid >> 3, rr = (tid >> 1) & 3, e = tid & 1;
            xs[cil][rr][e ? 65 : 0] = 0.f;
        }
        // stage 8ci x 4rows x 64w
        #pragma unroll 2
        for (int i = tid; i < 2048; i += 256){
            int cil = i >> 8, rr = (i >> 6) & 3, w = i & 63;
            int h = h0 - 1 + rr;
            float v = 0.f;
            if (h >= 0 && h < HH) v = sbase[(long)(chunk*8+cil)*ci_stride + h*WW + w];
            xs[cil][rr][1+w] = v;
        }
        __syncthreads();
        #pragma unroll
        for (int cil = 0; cil < 8; ++cil){
            const int cig = chunk*8 + cil;
            #pragma unroll
            for (int kh = 0; kh < 3; ++kh){
                const float* xr = &xs[cil][row+kh][w0];   // [w0-1+j] -> xr[j]
                float xv0=xr[0],xv1=xr[1],xv2=xr[2],xv3=xr[3],xv4=xr[4],xv5=xr[5];
                const float* wp = &lw[(cig*9 + kh*3)*32 + co0];
                #pragma unroll
                for (int kw = 0; kw < 3; ++kw){
                    float4 wa = *(const float4*)(wp + kw*32);
                    float x0 = (kw==0)?xv0:((kw==1)?xv1:xv2);
                    float x1 = (kw==0)?xv1:((kw==1)?xv2:xv3);
                    float x2 = (kw==0)?xv2:((kw==1)?xv3:xv4);
                    float x3 = (kw==0)?xv3:((kw==1)?xv4:xv5);
                    acc[0][0] += x0*wa.x; acc[0][1] += x1*wa.x; acc[0][2] += x2*wa.x; acc[0][3] += x3*wa.x;
                    acc[1][0] += x0*wa.y; acc[1][1] += x1*wa.y; acc[1][2] += x2*wa.y; acc[1][3] += x3*wa.y;
                    acc[2][0] += x0*wa.z; acc[2][1] += x1*wa.z; acc[2][2] += x2*wa.z; acc[2][3] += x3*wa.z;
                    acc[3][0] += x0*wa.w; acc[3][1] += x1*wa.w; acc[3][2] += x2*wa.w; acc[3][3] += x3*wa.w;
                }
            }
        }
    }

    if (MODE == 0){
        const int h = h0 + row;
        float* dst = ws + OFF_F1 + (((long)l*CC)*HH + h)*WW + w0;
        #pragma unroll
        for (int i = 0; i < 4; ++i){
            float bias = cb[co0+i];
            float4 o;
            float a0 = acc[i][0]+bias, a1 = acc[i][1]+bias, a2 = acc[i][2]+bias, a3 = acc[i][3]+bias;
            o.x = a0*sigmoidf_(a0); o.y = a1*sigmoidf_(a1);
            o.z = a2*sigmoidf_(a2); o.w = a3*sigmoidf_(a3);
            *(float4*)(dst + (long)(co0+i)*HH*WW) = o;
        }
    } else {
        __syncthreads();
        #pragma unroll
        for (int i = 0; i < 4; ++i){
            float bias = cb[co0+i];
            #pragma unroll
            for (int j = 0; j < 4; ++j){
                float a = acc[i][j] + bias;
                a = a*sigmoidf_(a);
                atomicAdd(&red[(co0+i)*WW + w0 + j], a);
            }
        }
        __syncthreads();
        // 2048 values, 256 threads: co = t>>3, wseg = (t&7)*8
        int co = tid >> 3, wseg = (tid & 7)*8;
        float s = 0.f;
        #pragma unroll
        for (int j = 0; j < 8; ++j){
            float v = red[co*WW + wseg + j];
            s += v;
            atomicAdd(&ws[OFF_COLSUM + (l*CC+co)*WW + wseg + j], v);
        }
        s += __shfl_down(s, 4, 8);
        s += __shfl_down(s, 2, 8);
        s += __shfl_down(s, 1, 8);
        if ((tid & 7) == 0) atomicAdd(&ws[OFF_GSUM + l*CC + co], s);
    }
}

// ---- K3: glob ----
__global__ void k_glob(const float* __restrict__ gfc_w, const float* __restrict__ gfc_b,
                       float* __restrict__ ws){
    int t = blockIdx.x*blockDim.x + threadIdx.x;
    if (t >= LL*CC) return;
    int l = t >> 5, o = t & 31;
    const float* gs = ws + OFF_GSUM + l*CC;
    float acc = gfc_b[o];
    for (int i=0;i<CC;i++) acc += gs[i]*(1.0f/4096.0f)*gfc_w[o*CC+i];
    ws[OFF_GLOB + t] = sigmoidf_(acc);
}

// ---- K4: adaptive pool * glob ----
__global__ void k_feat(float* __restrict__ ws){
    int t = blockIdx.x*blockDim.x + threadIdx.x;
    if (t >= LL*WF*CC) return;
    int c = t & 31;
    int lw_ = t >> 5;
    int wf = lw_ % WF, l = lw_ / WF;
    int s = (wf*64)/33;
    int e = ((wf+1)*64 + 32)/33;
    const float* cs = ws + OFF_COLSUM + (l*CC+c)*WW;
    float sum = 0.f;
    for (int w=s;w<e;w++) sum += cs[w];
    ws[OFF_FEAT + (l*WF+wf)*CC + c] = ws[OFF_GLOB + l*CC + c] * sum / (64.0f*(float)(e-s));
}

// ---- K5: head ----
__global__ void k_head(const float* __restrict__ hw, const float* __restrict__ hb,
                       const float* __restrict__ dt, float* __restrict__ ws){
    int t = blockIdx.x*blockDim.x + threadIdx.x;
    if (t >= LL*WF*CC*RR) return;
    int r = t & 15, c = (t>>4) & 31;
    int lw_ = t >> 9;
    int wf = lw_ % WF, l = lw_ / WF;
    const float* feat = ws + OFF_FEAT + (l*WF+wf)*CC;
    int j0 = (c*RR + r)*3;
    const float* w0 = hw + j0*CC;
    float p0=hb[j0], p1=hb[j0+1], p2=hb[j0+2];
    for (int i=0;i<CC;i++){
        float fv = feat[i];
        p0 += fv*w0[i]; p1 += fv*w0[CC+i]; p2 += fv*w0[2*CC+i];
    }
    float nu = fmaxf(p0,0.f) + log1pf(expf(-fabsf(p0)));
    float th = tanhf(p1)*PI_F;
    float sg = sigmoidf_(p2);
    float dtv = dt[l];
    float decay = expf(-nu*dtv);
    float ang = th*dtv;
    float g = 1.0f - expf(-2.0f*fmaxf(dtv,0.f));
    int idx = ((l*CC+c)*WF+wf)*RR + r;
    ws[OFF_ARE+idx] = decay*cosf(ang);
    ws[OFF_AIM+idx] = decay*sinf(ang);
    ws[OFF_SGG+idx] = sg*g;
}

// ---- K6: rfft ----
__global__ void k_rfft(const float* __restrict__ x, float* __restrict__ ws){
    __shared__ float plane[HH][WW+1];
    __shared__ float ct[64], st[64];
    int b = blockIdx.x; int l = b >> 5, c = b & 31;
    int tid = threadIdx.x;
    if (tid < 64){
        float ang = 2.0f*PI_F*(float)tid/64.0f;
        ct[tid] = cosf(ang); st[tid] = sinf(ang);
    }
    const float* xp = x + (c*LL + l)*HH*WW;
    for (int k=0;k<16;k++){
        int pix = tid + k*256;
        plane[pix>>6][pix&63] = xp[pix];
    }
    __syncthreads();
    float* xfr = ws + OFF_XFR + (l*CC + c)*HH*WF;
    float* xfi = ws + OFF_XFI + (l*CC + c)*HH*WF;
    for (int k=0;k<9;k++){
        int oi = tid + k*256;
        if (oi >= HH*WF) break;
        int h = oi/WF, f = oi - h*WF;
        float re=0.f, im=0.f;
        int idx = 0;
        for (int w=0;w<WW;w++){
            float v = plane[h][w];
            re += v*ct[idx]; im -= v*st[idx];
            idx = (idx + f) & 63;
        }
        xfr[oi] = re; xfi[oi] = im;
    }
}

// ---- K7: scan ----
__global__ void k_scan(float* __restrict__ ws){
    __shared__ float wv[66];
    int tid = threadIdx.x;
    if (tid < 66) wv[tid] = ws[OFF_WVEC + tid];
    __syncthreads();
    int t = blockIdx.x*256 + tid;
    if (t >= CC*HH*WF) return;
    int f = t % WF;
    int c = t / (HH*WF);
    float sre[RR], sim[RR];
    #pragma unroll
    for (int r=0;r<RR;r++){ sre[r]=0.f; sim[r]=0.f; }
    for (int l=0;l<LL;l++){
        int base = ((l*CC+c)*WF+f)*RR;
        const float4* A4 = reinterpret_cast<const float4*>(ws + OFF_ARE + base);
        const float4* I4 = reinterpret_cast<const float4*>(ws + OFF_AIM + base);
        const float4* S4 = reinterpret_cast<const float4*>(ws + OFF_SGG + base);
        float ar[RR], ai[RR], sg[RR];
        #pragma unroll
        for (int q=0;q<4;q++){
            float4 a = A4[q], bb = I4[q], s = S4[q];
            ar[4*q]=a.x; ar[4*q+1]=a.y; ar[4*q+2]=a.z; ar[4*q+3]=a.w;
            ai[4*q]=bb.x; ai[4*q+1]=bb.y; ai[4*q+2]=bb.z; ai[4*q+3]=bb.w;
            sg[4*q]=s.x; sg[4*q+1]=s.y; sg[4*q+2]=s.z; sg[4*q+3]=s.w;
        }
        float xr = ws[OFF_XFR + l*(CC*HH*WF) + t];
        float xi = ws[OFF_XFI + l*(CC*HH*WF) + t];
        float yr = wv[64], yi = wv[65];
        #pragma unroll
        for (int r=0;r<RR;r++){
            float nre = ar[r]*sre[r] - ai[r]*sim[r] + sg[r]*xr;
            float nim = ar[r]*sim[r] + ai[r]*sre[r] + sg[r]*xi;
            sre[r]=nre; sim[r]=nim;
            yr += wv[r]*nre + wv[16+r]*nim;
            yi += wv[32+r]*nre + wv[48+r]*nim;
        }
        ws[OFF_YFR + l*(CC*HH*WF) + t] = yr;
        ws[OFF_YFI + l*(CC*HH*WF) + t] = yi;
    }
}

// ---- K8: irfft ----
__global__ void k_irfft(float* __restrict__ ws){
    __shared__ float yr[HH][WF], yi[HH][WF];
    __shared__ float ct[64], st[64];
    int b = blockIdx.x; int l = b>>5, c = b&31;
    int tid = threadIdx.x;
    if (tid < 64){ float ang = 2.f*PI_F*(float)tid/64.f; ct[tid]=cosf(ang); st[tid]=sinf(ang); }
    const float* Yr = ws + OFF_YFR + (l*CC+c)*HH*WF;
    const float* Yi = ws + OFF_YFI + (l*CC+c)*HH*WF;
    for (int k=0;k<9;k++){
        int i = tid + k*256;
        if (i < HH*WF){ int h=i/WF, f=i-h*WF; yr[h][f]=Yr[i]; yi[h][f]=Yi[i]; }
    }
    __syncthreads();
    float* y1 = ws + OFF_Y1 + (l*CC+c)*HH*WW;
    for (int k=0;k<16;k++){
        int pix = tid + k*256;
        int h = pix>>6, w = pix&63;
        float acc = yr[h][0] + ((w&1)? -yr[h][32] : yr[h][32]);
        #pragma unroll
        for (int f=1;f<32;f++){
            int a = (f*w)&63;
            acc += 2.0f*(yr[h][f]*ct[a] - yi[h][f]*st[a]);
        }
        y1[pix] = acc*(1.0f/64.0f);
    }
}

// ---- K9: pif ----
__global__ void k_pif(const float* __restrict__ pw, const float* __restrict__ pb,
                      float* __restrict__ ws){
    __shared__ float row[CC][WW];
    int b = blockIdx.x; int l = b>>6, h = b&63;
    int tid = threadIdx.x;
    for (int k=0;k<8;k++){
        int i = tid + k*256;
        int ci = i>>6, w = i&63;
        row[ci][w] = ws[OFF_Y1 + ((l*CC+ci)*HH + h)*WW + w];
    }
    __syncthreads();
    for (int k=0;k<8;k++){
        int i = tid + k*256;
        int o = i>>6, w = i&63;
        float acc = pb[o];
        #pragma unroll
        for (int ci=0;ci<CC;ci++) acc += pw[o*CC+ci]*row[ci][w];
        ws[OFF_Y2 + ((l*CC+o)*HH + h)*WW + w] = acc;
    }
}

// ---- K10: GroupNorm stats ----
__global__ void k_gnstat(float* __restrict__ ws){
    __shared__ float rs[256], rq[256];
    int b = blockIdx.x; int l = b>>2, g = b&3;
    const float* z = ws + OFF_Y2 + (l*CC + g*8)*HH*WW;
    int tid = threadIdx.x;
    float s=0.f, q=0.f;
    for (int i=tid;i<8*HH*WW;i+=256){ float v=z[i]; s+=v; q+=v*v; }
    rs[tid]=s; rq[tid]=q; __syncthreads();
    for (int off=128; off>0; off>>=1){
        if (tid<off){ rs[tid]+=rs[tid+off]; rq[tid]+=rq[tid+off]; }
        __syncthreads();
    }
    if (tid==0){
        float mean = rs[0]/32768.0f;
        float var = rq[0]/32768.0f - mean*mean;
        ws[OFF_GNM + b] = mean;
        ws[OFF_GNR + b] = rsqrtf(var + 1e-5f);
    }
}

// ---- K11: normalize + W-mean ----
__global__ void k_normym(const float* __restrict__ gn_w, const float* __restrict__ gn_b,
                         float* __restrict__ ws){
    int b = blockIdx.x; int l = b>>5, c = b&31;
    int tid = threadIdx.x;
    int g = c>>3;
    float mu = ws[OFF_GNM + l*4+g], rstd = ws[OFF_GNR + l*4+g];
    float gw = gn_w[c], gb = gn_b[c];
    float* z = ws + OFF_Y2 + (l*CC+c)*HH*WW;
    int w = tid&63, hs = tid>>6;
    for (int k=0;k<16;k++){
        int h = hs*16 + k;
        int i = h*WW + w;
        float v = (z[i]-mu)*rstd*gw + gb;
        z[i] = v;
        float s = v;
        for (int off=32; off>0; off>>=1) s += __shfl_down(s, off, 64);
        if ((tid&63)==0) ws[OFF_YM + (l*HH+h)*CC + c] = s*(1.0f/64.0f);
    }
}

// ---- K12: gate MLP ----
__global__ void k_gate(const float* __restrict__ g1w, const float* __restrict__ g1b,
                       const float* __restrict__ g2w, const float* __restrict__ g2b,
                       float* __restrict__ ws){
    int t = blockIdx.x*256 + threadIdx.x;
    if (t >= LL*HH*CC) return;
    int c = t & 31, h = (t>>5)&63, l = t>>11;
    const float* ym = ws + OFF_YM + (l*HH+h)*CC;
    float mid[4];
    #pragma unroll
    for (int m=0;m<4;m++){
        float a = g1b[m];
        for (int i=0;i<CC;i++) a += ym[i]*g1w[m*CC+i];
        mid[m] = a*sigmoidf_(a);
    }
    float a = g2b[c];
    #pragma unroll
    for (int m=0;m<4;m++) a += mid[m]*g2w[c*4+m];
    ws[OFF_GATE + t] = sigmoidf_(a);
}

// ---- K13: residual ----
__global__ void k_final(const float* __restrict__ x, float* __restrict__ out,
                        const float* __restrict__ ws){
    int t = blockIdx.x*256 + threadIdx.x;
    int w = t&63, h = (t>>6)&63, l = (t>>12)&15, c = t>>16;
    float z = ws[OFF_Y2 + ((l*CC+c)*HH+h)*WW + w];
    float gt = ws[OFF_GATE + (l*HH+h)*CC + c];
    out[t] = x[t] + z*gt;
}

extern "C" void kernel_launch(void* const* d_in, const int* in_sizes, int n_in,
                              void* d_out, int out_size, void* d_ws, size_t ws_size,
                              hipStream_t stream){
    const float* x    = (const float*)d_in[0];
    const float* dt   = (const float*)d_in[1];
    const float* c1w  = (const float*)d_in[2];
    const float* c1b  = (const float*)d_in[3];
    const float* c2w  = (const float*)d_in[4];
    const float* c2b  = (const float*)d_in[5];
    const float* gfcw = (const float*)d_in[6];
    const float* gfcb = (const float*)d_in[7];
    const float* hw   = (const float*)d_in[8];
    const float* hb   = (const float*)d_in[9];
    const float* mixw = (const float*)d_in[10];
    const float* mixb = (const float*)d_in[11];
    const float* rs   = (const float*)d_in[12];
    const float* pjw  = (const float*)d_in[13];
    const float* pjb  = (const float*)d_in[14];
    const float* pifw = (const float*)d_in[15];
    const float* pifb = (const float*)d_in[16];
    const float* gnw  = (const float*)d_in[17];
    const float* gnb  = (const float*)d_in[18];
    const float* g1w  = (const float*)d_in[19];
    const float* g1b  = (const float*)d_in[20];
    const float* g2w  = (const float*)d_in[21];
    const float* g2b  = (const float*)d_in[22];
    float* ws  = (float*)d_ws;
    float* out = (float*)d_out;

    k_prep  <<<1,    64,  0, stream>>>(mixw, mixb, rs, pjw, pjb, ws);
    // conv1: src = x, layout [C][L][H][W]
    k_conv<0><<<512, 256, 0, stream>>>(x, (long)LL*HH*WW, (long)HH*WW, c1w, c1b, ws);
    hipMemsetAsync((void*)(ws + OFF_COLSUM), 0, (32768+512)*sizeof(float), stream);
    // conv2: src = f1 in ws, layout [L][C][H][W]
    k_conv<1><<<512, 256, 0, stream>>>(ws + OFF_F1, (long)HH*WW, (long)CC*HH*WW, c2w, c2b, ws);
    k_glob  <<<2,    256, 0, stream>>>(gfcw, gfcb, ws);
    k_feat  <<<66,   256, 0, stream>>>(ws);
    k_head  <<<1056, 256, 0, stream>>>(hw, hb, dt, ws);
    k_rfft  <<<512,  256, 0, stream>>>(x, ws);
    k_scan  <<<264,  256, 0, stream>>>(ws);
    k_irfft <<<512,  256, 0, stream>>>(ws);
    k_pif   <<<1024, 256, 0, stream>>>(pifw, pifb, ws);
    k_gnstat<<<64,   256, 0, stream>>>(ws);
    k_normym<<<512,  256, 0, stream>>>(gnw, gnb, ws);
    k_gate  <<<128,  256, 0, stream>>>(g1w, g1b, g2w, g2b, ws);
    k_final <<<8192, 256, 0, stream>>>(x, out, ws);
}